// Round 5
// baseline (340.598 us; speedup 1.0000x reference)
//
#include <hip/hip_runtime.h>
#include <math.h>

#define T_TOKENS 4096
#define HIDDEN   2048
#define N_EXPERTS 8
#define N_ROWS   (N_EXPERTS * T_TOKENS)   // 32768 rows of router_indices
#define ROW_F4   (HIDDEN / 4)             // 512 float4 per row

// R7 = MEASUREMENT ROUND. R3's fused kernel (113 us of our-time) + a second,
// idempotent fill pass appended at the end (each wave rewrites the rows of
// wave (gw+4096)&8191 with identical values; shifted by half the buffer so
// pass-2 lines are mostly evicted from L2 by the time they're rewritten ->
// real HBM writes). dur_us - 302.2 measures the marginal cost of ONE fill:
//   ~95-105 -> fill runs at ~2.7 TB/s in our kernels (vs rocclr 6.4) -> pig
//   ~45-55  -> fill is near-rocclr; the router's ~50 us is the pig
// Bonus: if fill is slow, this dispatch is ~205 us -> visible in top-5 with
// full counters (first sighting since R1).
#define NBLOCKS 2048

__global__ __launch_bounds__(256) void fused_router_fill2(
    const float* __restrict__ h, const float* __restrict__ w,
    float* __restrict__ out0, float* __restrict__ out1, float* __restrict__ out2)
{
    const int wave = threadIdx.x >> 6;
    const int lane = threadIdx.x & 63;
    const int gw   = blockIdx.x * 4 + wave;     // global wave id, 0..8191
    const bool is_router = (gw < T_TOKENS);

    const float4* h4 = (const float4*)h;
    const float4* w4 = (const float4*)w;

    // ---- 1. issue the whole 8 KB token row (8 independent 1 KB loads) ----
    float4 hv[8];
    if (is_router) {
        #pragma unroll
        for (int j = 0; j < 8; j++)
            hv[j] = h4[(size_t)gw * ROW_F4 + j * 64 + lane];
    }

    // ---- 2. fill pass 1: 4 contiguous rows (32 KB of stores), all waves ----
    {
        float4* o4 = (float4*)out1;
        const int r0 = gw * 4;
        #pragma unroll
        for (int i = 0; i < 4; i++) {
            float v = (float)((r0 + i) & (T_TOKENS - 1));
            float4 vv = make_float4(v, v, v, v);
            float4* rowp = o4 + (size_t)(r0 + i) * ROW_F4;
            #pragma unroll
            for (int j = 0; j < 8; j++)
                rowp[j * 64 + lane] = vv;
        }
    }

    // ---- 3. router role: 8 expert dots + reduce + top-2 + sigmoid ----
    if (is_router) {
        float acc[N_EXPERTS];
        #pragma unroll
        for (int e = 0; e < N_EXPERTS; e++) acc[e] = 0.f;

        #pragma unroll
        for (int e = 0; e < N_EXPERTS; e++) {
            #pragma unroll
            for (int j = 0; j < 8; j++) {
                float4 wv = w4[e * ROW_F4 + j * 64 + lane];
                acc[e] += hv[j].x * wv.x + hv[j].y * wv.y
                        + hv[j].z * wv.z + hv[j].w * wv.w;
            }
        }

        // 64-lane shuffle reduction per expert
        #pragma unroll
        for (int e = 0; e < N_EXPERTS; e++) {
            #pragma unroll
            for (int off = 32; off > 0; off >>= 1)
                acc[e] += __shfl_down(acc[e], off, 64);
        }

        if (lane == 0) {
            // top-2 of 8; strict > keeps first index on ties (== lax.top_k)
            int i1 = 0; float v1 = acc[0];
            #pragma unroll
            for (int e = 1; e < N_EXPERTS; e++)
                if (acc[e] > v1) { v1 = acc[e]; i1 = e; }
            int i2 = -1; float v2 = -INFINITY;
            #pragma unroll
            for (int e = 0; e < N_EXPERTS; e++)
                if (e != i1 && acc[e] > v2) { v2 = acc[e]; i2 = e; }

            float s1 = 1.f / (1.f + expf(-v1));
            float s2 = 1.f / (1.f + expf(-v2));

            #pragma unroll
            for (int e = 0; e < N_EXPERTS; e++) {
                float val = (e == i1) ? s1 : ((e == i2) ? s2 : 0.f);
                out0[e * T_TOKENS + gw] = val;
                out2[e * T_TOKENS + gw] = val;
            }
        }
    }

    // ---- 4. fill pass 2 (MEASUREMENT ONLY, idempotent): rewrite the rows
    // of wave (gw+4096)&8191. Same values -> benign WW race with pass 1.
    {
        float4* o4 = (float4*)out1;
        const int gw2 = (gw + 4096) & 8191;
        const int r0 = gw2 * 4;
        #pragma unroll
        for (int i = 0; i < 4; i++) {
            float v = (float)((r0 + i) & (T_TOKENS - 1));
            float4 vv = make_float4(v, v, v, v);
            float4* rowp = o4 + (size_t)(r0 + i) * ROW_F4;
            #pragma unroll
            for (int j = 0; j < 8; j++)
                rowp[j * 64 + lane] = vv;
        }
    }
}

extern "C" void kernel_launch(void* const* d_in, const int* in_sizes, int n_in,
                              void* d_out, int out_size, void* d_ws, size_t ws_size,
                              hipStream_t stream) {
    const float* h = (const float*)d_in[0];   // [4096, 2048] f32
    const float* w = (const float*)d_in[1];   // [8, 2048] f32
    // d_in[2] = top_k (always 2 for this problem)

    float* out  = (float*)d_out;
    float* out0 = out;                                            // router_scores [8,4096]
    float* out1 = out + N_EXPERTS * T_TOKENS;                     // router_indices [32768,2048]
    float* out2 = out1 + (size_t)N_EXPERTS * T_TOKENS * HIDDEN;   // router_probs [32768,1]

    hipLaunchKernelGGL(fused_router_fill2, dim3(NBLOCKS), dim3(256), 0, stream,
                       h, w, out0, out1, out2);
}